// Round 7
// baseline (203.534 us; speedup 1.0000x reference)
//
#include <hip/hip_runtime.h>
#include <hip/hip_bf16.h>
#include <math.h>

static constexpr int kC = 32, kR = 255, kE = 256;

// Static device scratch (graph-capture-safe). No atomics (round-5 lesson).
__device__ float g_vc[256];              // W_v·cls + b_v
__device__ float g_qw[4 * 256];          // (q0_h^T W_k,h)*scale  [h][e]
__device__ float g_s0[4];                // score of key position 0 per head
__device__ float g_qb[4];                // (q0_h · b_k,h)*scale
__device__ float g_m[256 * 4 * 4];       // chunk max   [bc][chunk][h]
__device__ float g_l[256 * 4 * 4];       // chunk sum   [bc][chunk][h]
__device__ float g_part[256 * 4 * 4 * 256]; // partial xbar [bc][chunk][h][e]
__device__ float g_ln[256 * 256];        // LN output per token
__device__ float g_hact[256 * 1024];     // FFN hidden activations
// bf16 weight caches in e8-major TRANSPOSED layout:  W8[e8][o][8] i.e.
// index ((e>>3)*OUT + o)*8 + (e&7).  Thread t==o reads uint4 at
// (e8*OUT+t)*16B -> lane-consecutive, fully coalesced (round-6 lesson:
// row-per-thread on row-major weights = 64-line scatter, ~22 GB/s/CU).
__device__ unsigned short g_wv_bf[256 * 256];    // OUT=256, IN=256
__device__ unsigned short g_wout_bf[256 * 256];  // OUT=256, IN=256
__device__ unsigned short g_w1_bf[1024 * 256];   // OUT=1024, IN=256
__device__ unsigned short g_w2_bf[256 * 1024];   // OUT=256, IN=1024

__device__ inline unsigned short f2bf(float f) {
  __hip_bfloat16 h = __float2bfloat16(f);
  return __builtin_bit_cast(unsigned short, h);
}
__device__ inline float bflo(unsigned int u) { return __uint_as_float(u << 16); }
__device__ inline float bfhi(unsigned int u) { return __uint_as_float(u & 0xffff0000u); }

// ---- Setup: blocks 0..3 per-head math (coalesced wave-per-row);
//      blocks 4..643 fp32->bf16 transposing casts. ----
__global__ __launch_bounds__(256) void k_setup(const float* __restrict__ cls,
                                               const float* __restrict__ w_qkv,
                                               const float* __restrict__ b_qkv,
                                               const float* __restrict__ w_out,
                                               const float* __restrict__ w1,
                                               const float* __restrict__ w2) {
  const int t = threadIdx.x, wvi = t >> 6, l = t & 63;
  if (blockIdx.x >= 4) {  // ---- transposing cast blocks: 1024 elements each ----
    const int u = blockIdx.x - 4;  // 0..639
    const float* src;
    unsigned short* dst;
    int OUT, insh;
    size_t idx0;
    if (u < 64) { src = w_qkv + 512 * 256; dst = g_wv_bf; OUT = 256; insh = 8; idx0 = (size_t)u * 1024; }
    else if (u < 128) { src = w_out; dst = g_wout_bf; OUT = 256; insh = 8; idx0 = (size_t)(u - 64) * 1024; }
    else if (u < 384) { src = w1; dst = g_w1_bf; OUT = 1024; insh = 8; idx0 = (size_t)(u - 128) * 1024; }
    else { src = w2; dst = g_w2_bf; OUT = 256; insh = 10; idx0 = (size_t)(u - 384) * 1024; }
    const size_t idx = idx0 + (size_t)t * 4;
    const int o = (int)(idx >> insh), e = (int)(idx & ((1 << insh) - 1));
    float4 v = *(const float4*)(src + idx);
    ushort4 ov;
    ov.x = f2bf(v.x); ov.y = f2bf(v.y); ov.z = f2bf(v.z); ov.w = f2bf(v.w);
    *(ushort4*)(dst + ((size_t)(e >> 3) * OUT + o) * 8 + (e & 7)) = ov;
    return;
  }

  // ---- head-math block h: only this head's 64 q/k/v rows, wave-per-row ----
  const int h = blockIdx.x;
  __shared__ float clss[256], q0h[64], kch[64];
  clss[t] = cls[t];
  __syncthreads();
  const float4 c4v = *((const float4*)clss + l);
  for (int r = wvi; r < 192; r += 4) {  // kind 0=q,1=k,2=v ; row chunk = 1 KB = 64 lanes x 16B
    const int kind = r >> 6, j = r & 63;
    const int row = kind * 256 + h * 64 + j;
    const float4 w4 = *((const float4*)(w_qkv + (size_t)row * 256) + l);
    float a = w4.x * c4v.x + w4.y * c4v.y + w4.z * c4v.z + w4.w * c4v.w;
#pragma unroll
    for (int m = 1; m < 64; m <<= 1) a += __shfl_xor(a, m);
    if (l == 0) {
      const float val = a + b_qkv[row];
      if (kind == 0) q0h[j] = val;
      else if (kind == 1) kch[j] = val;
      else g_vc[h * 64 + j] = val;
    }
  }
  __syncthreads();
  {  // qw[h][t] (coalesced over t)
    float acc = 0.f;
#pragma unroll 8
    for (int j = 0; j < 64; ++j)
      acc += q0h[j] * w_qkv[(size_t)(256 + h * 64 + j) * 256 + t];
    g_qw[h * 256 + t] = acc * 0.125f;
  }
  if (wvi == 0) {
    const float q = q0h[l];
    float pk = q * kch[l], pb = q * b_qkv[256 + h * 64 + l];
#pragma unroll
    for (int m = 1; m < 64; m <<= 1) {
      pk += __shfl_xor(pk, m);
      pb += __shfl_xor(pb, m);
    }
    if (l == 0) {
      g_s0[h] = pk * 0.125f;
      g_qb[h] = pb * 0.125f;
    }
  }
}

// ---- Attention chunks: scores + chunk softmax + partial weighted sums ----
__global__ __launch_bounds__(256) void k_attn(const float* __restrict__ x,
                                              const int* __restrict__ real_cols,
                                              const int* __restrict__ real_rows) {
  const int bc = blockIdx.x, chunk = blockIdx.y;
  const int b = bc >> 5, c = bc & 31;
  if (c >= real_cols[b]) return;
  const int rr = real_rows[b];
  const int r0 = chunk * 64;
  const int nr = min(64, rr - r0);
  if (nr <= 0) return;

  __shared__ float xs[64][260];  // 1040B row stride: uniform bank windows
  __shared__ float qws[4][256];
  __shared__ float ps[4][64];
  const int t = threadIdx.x, wv = t >> 6, l = t & 63;

#pragma unroll
  for (int i = 0; i < 4; ++i) qws[i][t] = g_qw[i * 256 + t];

  const float* xb = x + ((size_t)bc * kR + r0) * kE;
  for (int r = wv; r < nr; r += 4)
    *(float4*)&xs[r][4 * l] = *(const float4*)(xb + (size_t)r * kE + 4 * l);
  __syncthreads();

  const int h = wv, row = l;
  float acc = 0.f;
  const float4* qrow = (const float4*)&qws[h][0];
  const float4* xrow = (const float4*)&xs[row][0];
#pragma unroll 8
  for (int e4 = 0; e4 < 64; ++e4) {
    float4 q4 = qrow[e4];
    float4 x4 = xrow[e4];
    acc += q4.x * x4.x + q4.y * x4.y + q4.z * x4.z + q4.w * x4.w;
  }
  float s = (row < nr) ? acc + g_qb[h] : -1e30f;
  float mx = s;
#pragma unroll
  for (int m = 1; m < 64; m <<= 1) mx = fmaxf(mx, __shfl_xor(mx, m));
  float p = (row < nr) ? __expf(s - mx) : 0.f;
  float lsum = p;
#pragma unroll
  for (int m = 1; m < 64; m <<= 1) lsum += __shfl_xor(lsum, m);
  ps[h][row] = p;
  if (l == 0) {
    g_m[(bc * 4 + chunk) * 4 + h] = mx;
    g_l[(bc * 4 + chunk) * 4 + h] = lsum;
  }
  __syncthreads();

  float a0 = 0.f, a1 = 0.f, a2 = 0.f, a3 = 0.f;
  for (int r2 = 0; r2 < nr; ++r2) {
    float xv = xs[r2][t];
    a0 += ps[0][r2] * xv;
    a1 += ps[1][r2] * xv;
    a2 += ps[2][r2] * xv;
    a3 += ps[3][r2] * xv;
  }
  float* pp = g_part + (size_t)(bc * 4 + chunk) * 4 * 256;
  pp[0 * 256 + t] = a0;
  pp[1 * 256 + t] = a1;
  pp[2 * 256 + t] = a2;
  pp[3 * 256 + t] = a3;
}

// ---- Tail: merge -> xbar -> ctx -> mha -> LN. 1 token/block, coalesced. ----
__global__ __launch_bounds__(256) void k_tail(const int* __restrict__ real_cols,
                                              const int* __restrict__ real_rows,
                                              const float* __restrict__ b_qkv,
                                              const float* __restrict__ b_out,
                                              const float* __restrict__ ln_g,
                                              const float* __restrict__ ln_b) {
  const int bc = blockIdx.x, b = bc >> 5, c = bc & 31;
  if (c >= real_cols[b]) return;  // g_ln stays stale-but-finite; masked later
  const int rr = real_rows[b];
  const int nch = (rr + 63) >> 6;
  const int t = threadIdx.x, wv = t >> 6, l = t & 63;

  __shared__ float xb[4][256];
  __shared__ float ctxs[256];
  __shared__ float al[4][4];
  __shared__ float p0s[4];
  __shared__ float rb[2][4];

  if (t < 4) {  // flash-merge chunk stats, head h = t
    const int h = t;
    const float s0 = g_s0[h];
    float M = s0;
    for (int ch = 0; ch < nch; ++ch) M = fmaxf(M, g_m[(bc * 4 + ch) * 4 + h]);
    float lt = __expf(s0 - M);
    const float w0 = lt;
    float av[4] = {0.f, 0.f, 0.f, 0.f};
    for (int ch = 0; ch < nch; ++ch) {
      float e = __expf(g_m[(bc * 4 + ch) * 4 + h] - M);
      av[ch] = e;
      lt += g_l[(bc * 4 + ch) * 4 + h] * e;
    }
    const float inv = 1.f / lt;
#pragma unroll
    for (int ch = 0; ch < 4; ++ch) al[h][ch] = av[ch] * inv;
    p0s[h] = w0 * inv;
  }
  __syncthreads();

#pragma unroll
  for (int h = 0; h < 4; ++h) {
    float a = 0.f;
    for (int ch = 0; ch < nch; ++ch)
      a += al[h][ch] * g_part[(size_t)(bc * 4 + ch) * 4 * 256 + h * 256 + t];
    xb[h][t] = a;
  }
  __syncthreads();

  {  // ctx[f=t]; e8-major W_v: load (e8*256+t) -> coalesced
    const int h = wv;
    const float p0 = p0s[h];
    float acc = p0 * g_vc[t] + (1.f - p0) * b_qkv[512 + t];
    const uint4* wr = (const uint4*)g_wv_bf;
    const float4* v4p = (const float4*)&xb[h][0];
#pragma unroll 4
    for (int e8 = 0; e8 < 32; ++e8) {
      uint4 w = wr[e8 * 256 + t];
      float4 a = v4p[2 * e8], bb = v4p[2 * e8 + 1];
      acc += bflo(w.x) * a.x + bfhi(w.x) * a.y + bflo(w.y) * a.z + bfhi(w.y) * a.w +
             bflo(w.z) * bb.x + bfhi(w.z) * bb.y + bflo(w.w) * bb.z + bfhi(w.w) * bb.w;
    }
    ctxs[t] = acc;
  }
  __syncthreads();

  float mh;
  {  // mha[g=t]; e8-major W_out
    float acc = b_out[t];
    const uint4* wr = (const uint4*)g_wout_bf;
    const float4* c4 = (const float4*)&ctxs[0];
#pragma unroll 4
    for (int e8 = 0; e8 < 32; ++e8) {
      uint4 w = wr[e8 * 256 + t];
      float4 a = c4[2 * e8], bb = c4[2 * e8 + 1];
      acc += bflo(w.x) * a.x + bfhi(w.x) * a.y + bflo(w.y) * a.z + bfhi(w.y) * a.w +
             bflo(w.z) * bb.x + bfhi(w.z) * bb.y + bflo(w.w) * bb.z + bfhi(w.w) * bb.w;
    }
    mh = acc;
  }

  float s1 = mh, s2 = mh * mh;
#pragma unroll
  for (int m = 1; m < 64; m <<= 1) {
    s1 += __shfl_xor(s1, m);
    s2 += __shfl_xor(s2, m);
  }
  if (l == 0) {
    rb[0][wv] = s1;
    rb[1][wv] = s2;
  }
  __syncthreads();
  const float mu = (rb[0][0] + rb[0][1] + rb[0][2] + rb[0][3]) * (1.f / 256.f);
  const float msq = (rb[1][0] + rb[1][1] + rb[1][2] + rb[1][3]) * (1.f / 256.f);
  const float var = msq - mu * mu;
  g_ln[(size_t)bc * 256 + t] =
      (mh - mu) * rsqrtf(var + 1e-5f) * ln_g[t] + ln_b[t];
}

// ---- FFN1: relu(W1·ln+b1); 8 tokens x 128-f slice; e8-major W1 ----
__global__ __launch_bounds__(256) void k_ffn1(const float* __restrict__ b1,
                                              const int* __restrict__ real_cols) {
  const int tok0 = blockIdx.x * 8;
  const int b = tok0 >> 5, c0 = tok0 & 31;
  if (c0 >= real_cols[b]) return;
  __shared__ float lns[8][256];
  const int t = threadIdx.x;
  const int f0 = blockIdx.y * 128;
#pragma unroll
  for (int i = 0; i < 8; ++i) lns[i][t] = g_ln[(size_t)(tok0 + i) * 256 + t];
  __syncthreads();
  const int f = f0 + (t & 127), half = t >> 7;
  const uint4* wr = (const uint4*)g_w1_bf;
  const float bb = b1[f];
  float acc[4] = {bb, bb, bb, bb};
  for (int e8 = 0; e8 < 32; ++e8) {
    uint4 w = wr[e8 * 1024 + f];  // lanes f..f+63 consecutive -> coalesced
    const float w0 = bflo(w.x), w1v = bfhi(w.x), w2v = bflo(w.y), w3 = bfhi(w.y);
    const float w4v = bflo(w.z), w5 = bfhi(w.z), w6 = bflo(w.w), w7 = bfhi(w.w);
#pragma unroll
    for (int k = 0; k < 4; ++k) {
      const int i = half * 4 + k;
      const float4 a = *(const float4*)&lns[i][8 * e8];
      const float4 bbv = *(const float4*)&lns[i][8 * e8 + 4];
      acc[k] += w0 * a.x + w1v * a.y + w2v * a.z + w3 * a.w +
                w4v * bbv.x + w5 * bbv.y + w6 * bbv.z + w7 * bbv.w;
    }
  }
#pragma unroll
  for (int k = 0; k < 4; ++k)
    g_hact[(size_t)(tok0 + half * 4 + k) * 1024 + f] = fmaxf(acc[k], 0.f);
}

// ---- FFN2 + residual + mask; 8 tokens x 32-e slice; e8-major W2 ----
__global__ __launch_bounds__(256) void k_ffn2(const float* __restrict__ b2,
                                              const int* __restrict__ real_cols,
                                              float* __restrict__ out) {
  const int t = threadIdx.x;
  const int tok0 = blockIdx.x * 8, e0 = blockIdx.y * 32;
  const int b = tok0 >> 5, c0 = tok0 & 31;
  const int ncols = real_cols[b];
  if (c0 >= ncols) {  // whole group invalid: just write the zero mask
    out[(size_t)(tok0 + (t >> 5)) * 256 + e0 + (t & 31)] = 0.f;
    return;
  }
  __shared__ float hs[8][1024];  // 32 KB
#pragma unroll
  for (int i = 0; i < 8; ++i) {
#pragma unroll
    for (int j = 0; j < 4; ++j)
      hs[i][j * 256 + t] = g_hact[(size_t)(tok0 + i) * 1024 + j * 256 + t];
  }
  __syncthreads();
  const int e = e0 + (t & 31), i = t >> 5;
  const int tok = tok0 + i, c = tok & 31;
  const uint4* wr = (const uint4*)g_w2_bf;
  const float4* h4 = (const float4*)&hs[i][0];
  float acc = b2[e];
  for (int f8 = 0; f8 < 128; ++f8) {
    uint4 w = wr[f8 * 256 + e];  // 32 consecutive e x 16B, shared across tokens
    float4 a = h4[2 * f8], bb = h4[2 * f8 + 1];
    acc += bflo(w.x) * a.x + bfhi(w.x) * a.y + bflo(w.y) * a.z + bfhi(w.y) * a.w +
           bflo(w.z) * bb.x + bfhi(w.z) * bb.y + bflo(w.w) * bb.z + bfhi(w.w) * bb.w;
  }
  const float lnv = g_ln[(size_t)tok * 256 + e];
  out[(size_t)tok * 256 + e] = (c < ncols) ? (lnv + acc) : 0.f;
}

extern "C" void kernel_launch(void* const* d_in, const int* in_sizes, int n_in,
                              void* d_out, int out_size, void* d_ws, size_t ws_size,
                              hipStream_t stream) {
  const float* x = (const float*)d_in[0];
  const int* real_cols = (const int*)d_in[1];
  const int* real_rows = (const int*)d_in[2];
  const float* cls = (const float*)d_in[3];
  const float* w_qkv = (const float*)d_in[4];
  const float* b_qkv = (const float*)d_in[5];
  const float* w_out = (const float*)d_in[6];
  const float* b_out = (const float*)d_in[7];
  const float* ln_g = (const float*)d_in[8];
  const float* ln_b = (const float*)d_in[9];
  const float* w1 = (const float*)d_in[10];
  const float* b1 = (const float*)d_in[11];
  const float* w2 = (const float*)d_in[12];
  const float* b2 = (const float*)d_in[13];
  float* out = (float*)d_out;
  (void)in_sizes; (void)n_in; (void)out_size; (void)d_ws; (void)ws_size;

  k_setup<<<644, 256, 0, stream>>>(cls, w_qkv, b_qkv, w_out, w1, w2);
  k_attn<<<dim3(256, 4), 256, 0, stream>>>(x, real_cols, real_rows);
  k_tail<<<256, 256, 0, stream>>>(real_cols, real_rows, b_qkv, b_out, ln_g, ln_b);
  k_ffn1<<<dim3(32, 8), 256, 0, stream>>>(b1, real_cols);
  k_ffn2<<<dim3(32, 8), 256, 0, stream>>>(b2, real_cols, out);
}

// Round 8
// 203.526 us; speedup vs baseline: 1.0000x; 1.0000x over previous
//
#include <hip/hip_runtime.h>
#include <hip/hip_bf16.h>
#include <math.h>

static constexpr int kC = 32, kR = 255, kE = 256;

// Static device scratch (graph-capture-safe). No atomics (round-5 lesson).
__device__ float g_vc[256];              // W_v·cls + b_v
__device__ float g_qw[4 * 256];          // (q0_h^T W_k,h)*scale  [h][e]
__device__ float g_s0[4];                // score of key position 0 per head
__device__ float g_qb[4];                // (q0_h · b_k,h)*scale
__device__ float g_m[256 * 4 * 4];       // chunk max   [bc][chunk][h]
__device__ float g_l[256 * 4 * 4];       // chunk sum   [bc][chunk][h]
__device__ float g_part[256 * 4 * 4 * 256]; // partial xbar [bc][chunk][h][e]
__device__ float g_ln[256 * 256];        // LN output per token
__device__ float g_hact[256 * 1024];     // FFN hidden activations
// bf16 weight caches in e8-major TRANSPOSED layout: index
// ((e>>3)*OUT + o)*8 + (e&7). Consumers load uint4 at (e8*OUT+t)*16B ->
// lane-consecutive, fully coalesced (round-6 lesson). Producer must write
// coalesced too -> LDS-tiled transpose (round-7 lesson: direct scattered
// 8B writes at 4KB stride = ~45us for 2.5MB).
__device__ unsigned short g_wv_bf[256 * 256];    // OUT=256, IN=256
__device__ unsigned short g_wout_bf[256 * 256];  // OUT=256, IN=256
__device__ unsigned short g_w1_bf[1024 * 256];   // OUT=1024, IN=256
__device__ unsigned short g_w2_bf[256 * 1024];   // OUT=256, IN=1024

__device__ inline unsigned short f2bf(float f) {
  __hip_bfloat16 h = __float2bfloat16(f);
  return __builtin_bit_cast(unsigned short, h);
}
__device__ inline float bflo(unsigned int u) { return __uint_as_float(u << 16); }
__device__ inline float bfhi(unsigned int u) { return __uint_as_float(u & 0xffff0000u); }

// ---- Setup: blocks 0..3 per-head math; blocks 4..43 LDS-tiled
//      transposing bf16 casts (64 rows x 256 cols per tile). ----
__global__ __launch_bounds__(256) void k_setup(const float* __restrict__ cls,
                                               const float* __restrict__ w_qkv,
                                               const float* __restrict__ b_qkv,
                                               const float* __restrict__ w_out,
                                               const float* __restrict__ w1,
                                               const float* __restrict__ w2) {
  const int t = threadIdx.x, wvi = t >> 6, l = t & 63;
  if (blockIdx.x >= 4) {  // ---- cast tiles ----
    const int u = blockIdx.x - 4;  // 0..39
    const float* src;
    unsigned short* dst;
    int R, C, o0, e0;
    if (u < 4) { src = w_qkv + 512 * 256; dst = g_wv_bf; R = 256; C = 256; o0 = u * 64; e0 = 0; }
    else if (u < 8) { src = w_out; dst = g_wout_bf; R = 256; C = 256; o0 = (u - 4) * 64; e0 = 0; }
    else if (u < 24) { src = w1; dst = g_w1_bf; R = 1024; C = 256; o0 = (u - 8) * 64; e0 = 0; }
    else { const int v = u - 24; src = w2; dst = g_w2_bf; R = 256; C = 1024; o0 = (v >> 2) * 64; e0 = (v & 3) * 256; }

    __shared__ unsigned short tile[64 * 258];  // stride 258 shorts (odd dwords)
    // read: wave-per-row, coalesced float4, convert to bf16
    for (int r = wvi; r < 64; r += 4) {
      float4 v = *((const float4*)(src + (size_t)(o0 + r) * C + e0) + l);
      ushort4 ov;
      ov.x = f2bf(v.x); ov.y = f2bf(v.y); ov.z = f2bf(v.z); ov.w = f2bf(v.w);
      *(ushort4*)&tile[r * 258 + 4 * l] = ov;
    }
    __syncthreads();
    // write: lane l -> output row o0+l; per e8, 16B per lane, 1KB/wave coalesced
    const int e80 = e0 >> 3;
    for (int e8l = wvi; e8l < 32; e8l += 4) {
      ushort4 a = *(const ushort4*)&tile[l * 258 + e8l * 8];
      ushort4 bgm = *(const ushort4*)&tile[l * 258 + e8l * 8 + 4];
      unsigned short* dp = dst + ((size_t)(e80 + e8l) * R + o0 + l) * 8;
      *(ushort4*)dp = a;
      *(ushort4*)(dp + 4) = bgm;
    }
    return;
  }

  // ---- head-math block h: only this head's 64 q/k/v rows, wave-per-row ----
  const int h = blockIdx.x;
  __shared__ float clss[256], q0h[64], kch[64];
  clss[t] = cls[t];
  __syncthreads();
  const float4 c4v = *((const float4*)clss + l);
  for (int r = wvi; r < 192; r += 4) {  // kind 0=q,1=k,2=v
    const int kind = r >> 6, j = r & 63;
    const int row = kind * 256 + h * 64 + j;
    const float4 w4 = *((const float4*)(w_qkv + (size_t)row * 256) + l);
    float a = w4.x * c4v.x + w4.y * c4v.y + w4.z * c4v.z + w4.w * c4v.w;
#pragma unroll
    for (int m = 1; m < 64; m <<= 1) a += __shfl_xor(a, m);
    if (l == 0) {
      const float val = a + b_qkv[row];
      if (kind == 0) q0h[j] = val;
      else if (kind == 1) kch[j] = val;
      else g_vc[h * 64 + j] = val;
    }
  }
  __syncthreads();
  {  // qw[h][t] (coalesced over t)
    float acc = 0.f;
#pragma unroll 8
    for (int j = 0; j < 64; ++j)
      acc += q0h[j] * w_qkv[(size_t)(256 + h * 64 + j) * 256 + t];
    g_qw[h * 256 + t] = acc * 0.125f;
  }
  if (wvi == 0) {
    const float q = q0h[l];
    float pk = q * kch[l], pb = q * b_qkv[256 + h * 64 + l];
#pragma unroll
    for (int m = 1; m < 64; m <<= 1) {
      pk += __shfl_xor(pk, m);
      pb += __shfl_xor(pb, m);
    }
    if (l == 0) {
      g_s0[h] = pk * 0.125f;
      g_qb[h] = pb * 0.125f;
    }
  }
}

// ---- Attention chunks: scores + chunk softmax + partial weighted sums ----
__global__ __launch_bounds__(256) void k_attn(const float* __restrict__ x,
                                              const int* __restrict__ real_cols,
                                              const int* __restrict__ real_rows) {
  const int bc = blockIdx.x, chunk = blockIdx.y;
  const int b = bc >> 5, c = bc & 31;
  if (c >= real_cols[b]) return;
  const int rr = real_rows[b];
  const int r0 = chunk * 64;
  const int nr = min(64, rr - r0);
  if (nr <= 0) return;

  __shared__ float xs[64][260];  // 1040B row stride: uniform bank windows
  __shared__ float qws[4][256];
  __shared__ float ps[4][64];
  const int t = threadIdx.x, wv = t >> 6, l = t & 63;

#pragma unroll
  for (int i = 0; i < 4; ++i) qws[i][t] = g_qw[i * 256 + t];

  const float* xb = x + ((size_t)bc * kR + r0) * kE;
  for (int r = wv; r < nr; r += 4)
    *(float4*)&xs[r][4 * l] = *(const float4*)(xb + (size_t)r * kE + 4 * l);
  __syncthreads();

  const int h = wv, row = l;
  float acc = 0.f;
  const float4* qrow = (const float4*)&qws[h][0];
  const float4* xrow = (const float4*)&xs[row][0];
#pragma unroll 8
  for (int e4 = 0; e4 < 64; ++e4) {
    float4 q4 = qrow[e4];
    float4 x4 = xrow[e4];
    acc += q4.x * x4.x + q4.y * x4.y + q4.z * x4.z + q4.w * x4.w;
  }
  float s = (row < nr) ? acc + g_qb[h] : -1e30f;
  float mx = s;
#pragma unroll
  for (int m = 1; m < 64; m <<= 1) mx = fmaxf(mx, __shfl_xor(mx, m));
  float p = (row < nr) ? __expf(s - mx) : 0.f;
  float lsum = p;
#pragma unroll
  for (int m = 1; m < 64; m <<= 1) lsum += __shfl_xor(lsum, m);
  ps[h][row] = p;
  if (l == 0) {
    g_m[(bc * 4 + chunk) * 4 + h] = mx;
    g_l[(bc * 4 + chunk) * 4 + h] = lsum;
  }
  __syncthreads();

  float a0 = 0.f, a1 = 0.f, a2 = 0.f, a3 = 0.f;
  for (int r2 = 0; r2 < nr; ++r2) {
    float xv = xs[r2][t];
    a0 += ps[0][r2] * xv;
    a1 += ps[1][r2] * xv;
    a2 += ps[2][r2] * xv;
    a3 += ps[3][r2] * xv;
  }
  float* pp = g_part + (size_t)(bc * 4 + chunk) * 4 * 256;
  pp[0 * 256 + t] = a0;
  pp[1 * 256 + t] = a1;
  pp[2 * 256 + t] = a2;
  pp[3 * 256 + t] = a3;
}

// ---- Tail: merge -> xbar -> ctx -> mha -> LN. 1 token/block, coalesced. ----
__global__ __launch_bounds__(256) void k_tail(const int* __restrict__ real_cols,
                                              const int* __restrict__ real_rows,
                                              const float* __restrict__ b_qkv,
                                              const float* __restrict__ b_out,
                                              const float* __restrict__ ln_g,
                                              const float* __restrict__ ln_b) {
  const int bc = blockIdx.x, b = bc >> 5, c = bc & 31;
  if (c >= real_cols[b]) return;  // g_ln stays stale-but-finite; masked later
  const int rr = real_rows[b];
  const int nch = (rr + 63) >> 6;
  const int t = threadIdx.x, wv = t >> 6, l = t & 63;

  __shared__ float xb[4][256];
  __shared__ float ctxs[256];
  __shared__ float al[4][4];
  __shared__ float p0s[4];
  __shared__ float rb[2][4];

  if (t < 4) {  // flash-merge chunk stats, head h = t
    const int h = t;
    const float s0 = g_s0[h];
    float M = s0;
    for (int ch = 0; ch < nch; ++ch) M = fmaxf(M, g_m[(bc * 4 + ch) * 4 + h]);
    float lt = __expf(s0 - M);
    const float w0 = lt;
    float av[4] = {0.f, 0.f, 0.f, 0.f};
    for (int ch = 0; ch < nch; ++ch) {
      float e = __expf(g_m[(bc * 4 + ch) * 4 + h] - M);
      av[ch] = e;
      lt += g_l[(bc * 4 + ch) * 4 + h] * e;
    }
    const float inv = 1.f / lt;
#pragma unroll
    for (int ch = 0; ch < 4; ++ch) al[h][ch] = av[ch] * inv;
    p0s[h] = w0 * inv;
  }
  __syncthreads();

#pragma unroll
  for (int h = 0; h < 4; ++h) {
    float a = 0.f;
    for (int ch = 0; ch < nch; ++ch)
      a += al[h][ch] * g_part[(size_t)(bc * 4 + ch) * 4 * 256 + h * 256 + t];
    xb[h][t] = a;
  }
  __syncthreads();

  {  // ctx[f=t]; e8-major W_v: load (e8*256+t) -> coalesced
    const int h = wv;
    const float p0 = p0s[h];
    float acc = p0 * g_vc[t] + (1.f - p0) * b_qkv[512 + t];
    const uint4* wr = (const uint4*)g_wv_bf;
    const float4* v4p = (const float4*)&xb[h][0];
#pragma unroll 4
    for (int e8 = 0; e8 < 32; ++e8) {
      uint4 w = wr[e8 * 256 + t];
      float4 a = v4p[2 * e8], bb = v4p[2 * e8 + 1];
      acc += bflo(w.x) * a.x + bfhi(w.x) * a.y + bflo(w.y) * a.z + bfhi(w.y) * a.w +
             bflo(w.z) * bb.x + bfhi(w.z) * bb.y + bflo(w.w) * bb.z + bfhi(w.w) * bb.w;
    }
    ctxs[t] = acc;
  }
  __syncthreads();

  float mh;
  {  // mha[g=t]; e8-major W_out
    float acc = b_out[t];
    const uint4* wr = (const uint4*)g_wout_bf;
    const float4* c4 = (const float4*)&ctxs[0];
#pragma unroll 4
    for (int e8 = 0; e8 < 32; ++e8) {
      uint4 w = wr[e8 * 256 + t];
      float4 a = c4[2 * e8], bb = c4[2 * e8 + 1];
      acc += bflo(w.x) * a.x + bfhi(w.x) * a.y + bflo(w.y) * a.z + bfhi(w.y) * a.w +
             bflo(w.z) * bb.x + bfhi(w.z) * bb.y + bflo(w.w) * bb.z + bfhi(w.w) * bb.w;
    }
    mh = acc;
  }

  float s1 = mh, s2 = mh * mh;
#pragma unroll
  for (int m = 1; m < 64; m <<= 1) {
    s1 += __shfl_xor(s1, m);
    s2 += __shfl_xor(s2, m);
  }
  if (l == 0) {
    rb[0][wv] = s1;
    rb[1][wv] = s2;
  }
  __syncthreads();
  const float mu = (rb[0][0] + rb[0][1] + rb[0][2] + rb[0][3]) * (1.f / 256.f);
  const float msq = (rb[1][0] + rb[1][1] + rb[1][2] + rb[1][3]) * (1.f / 256.f);
  const float var = msq - mu * mu;
  g_ln[(size_t)bc * 256 + t] =
      (mh - mu) * rsqrtf(var + 1e-5f) * ln_g[t] + ln_b[t];
}

// ---- FFN1: relu(W1·ln+b1); 8 tokens x 128-f slice; e8-major W1 ----
__global__ __launch_bounds__(256) void k_ffn1(const float* __restrict__ b1,
                                              const int* __restrict__ real_cols) {
  const int tok0 = blockIdx.x * 8;
  const int b = tok0 >> 5, c0 = tok0 & 31;
  if (c0 >= real_cols[b]) return;
  __shared__ float lns[8][256];
  const int t = threadIdx.x;
  const int f0 = blockIdx.y * 128;
#pragma unroll
  for (int i = 0; i < 8; ++i) lns[i][t] = g_ln[(size_t)(tok0 + i) * 256 + t];
  __syncthreads();
  const int f = f0 + (t & 127), half = t >> 7;
  const uint4* wr = (const uint4*)g_w1_bf;
  const float bb = b1[f];
  float acc[4] = {bb, bb, bb, bb};
  for (int e8 = 0; e8 < 32; ++e8) {
    uint4 w = wr[e8 * 1024 + f];  // lanes f..f+63 consecutive -> coalesced
    const float w0 = bflo(w.x), w1v = bfhi(w.x), w2v = bflo(w.y), w3 = bfhi(w.y);
    const float w4v = bflo(w.z), w5 = bfhi(w.z), w6 = bflo(w.w), w7 = bfhi(w.w);
#pragma unroll
    for (int k = 0; k < 4; ++k) {
      const int i = half * 4 + k;
      const float4 a = *(const float4*)&lns[i][8 * e8];
      const float4 bbv = *(const float4*)&lns[i][8 * e8 + 4];
      acc[k] += w0 * a.x + w1v * a.y + w2v * a.z + w3 * a.w +
                w4v * bbv.x + w5 * bbv.y + w6 * bbv.z + w7 * bbv.w;
    }
  }
#pragma unroll
  for (int k = 0; k < 4; ++k)
    g_hact[(size_t)(tok0 + half * 4 + k) * 1024 + f] = fmaxf(acc[k], 0.f);
}

// ---- FFN2 + residual + mask; 8 tokens x 32-e slice; e8-major W2 ----
__global__ __launch_bounds__(256) void k_ffn2(const float* __restrict__ b2,
                                              const int* __restrict__ real_cols,
                                              float* __restrict__ out) {
  const int t = threadIdx.x;
  const int tok0 = blockIdx.x * 8, e0 = blockIdx.y * 32;
  const int b = tok0 >> 5, c0 = tok0 & 31;
  const int ncols = real_cols[b];
  if (c0 >= ncols) {  // whole group invalid: just write the zero mask
    out[(size_t)(tok0 + (t >> 5)) * 256 + e0 + (t & 31)] = 0.f;
    return;
  }
  __shared__ float hs[8][1024];  // 32 KB
#pragma unroll
  for (int i = 0; i < 8; ++i) {
#pragma unroll
    for (int j = 0; j < 4; ++j)
      hs[i][j * 256 + t] = g_hact[(size_t)(tok0 + i) * 1024 + j * 256 + t];
  }
  __syncthreads();
  const int e = e0 + (t & 31), i = t >> 5;
  const int tok = tok0 + i, c = tok & 31;
  const uint4* wr = (const uint4*)g_w2_bf;
  const float4* h4 = (const float4*)&hs[i][0];
  float acc = b2[e];
  for (int f8 = 0; f8 < 128; ++f8) {
    uint4 w = wr[f8 * 256 + e];  // 32 consecutive e x 16B, shared across tokens
    float4 a = h4[2 * f8], bb = h4[2 * f8 + 1];
    acc += bflo(w.x) * a.x + bfhi(w.x) * a.y + bflo(w.y) * a.z + bfhi(w.y) * a.w +
           bflo(w.z) * bb.x + bfhi(w.z) * bb.y + bflo(w.w) * bb.z + bfhi(w.w) * bb.w;
  }
  const float lnv = g_ln[(size_t)tok * 256 + e];
  out[(size_t)tok * 256 + e] = (c < ncols) ? (lnv + acc) : 0.f;
}

extern "C" void kernel_launch(void* const* d_in, const int* in_sizes, int n_in,
                              void* d_out, int out_size, void* d_ws, size_t ws_size,
                              hipStream_t stream) {
  const float* x = (const float*)d_in[0];
  const int* real_cols = (const int*)d_in[1];
  const int* real_rows = (const int*)d_in[2];
  const float* cls = (const float*)d_in[3];
  const float* w_qkv = (const float*)d_in[4];
  const float* b_qkv = (const float*)d_in[5];
  const float* w_out = (const float*)d_in[6];
  const float* b_out = (const float*)d_in[7];
  const float* ln_g = (const float*)d_in[8];
  const float* ln_b = (const float*)d_in[9];
  const float* w1 = (const float*)d_in[10];
  const float* b1 = (const float*)d_in[11];
  const float* w2 = (const float*)d_in[12];
  const float* b2 = (const float*)d_in[13];
  float* out = (float*)d_out;
  (void)in_sizes; (void)n_in; (void)out_size; (void)d_ws; (void)ws_size;

  k_setup<<<44, 256, 0, stream>>>(cls, w_qkv, b_qkv, w_out, w1, w2);
  k_attn<<<dim3(256, 4), 256, 0, stream>>>(x, real_cols, real_rows);
  k_tail<<<256, 256, 0, stream>>>(real_cols, real_rows, b_qkv, b_out, ln_g, ln_b);
  k_ffn1<<<dim3(32, 8), 256, 0, stream>>>(b1, real_cols);
  k_ffn2<<<dim3(32, 8), 256, 0, stream>>>(b2, real_cols, out);
}

// Round 9
// 180.526 us; speedup vs baseline: 1.1274x; 1.1274x over previous
//
#include <hip/hip_runtime.h>
#include <hip/hip_bf16.h>
#include <math.h>

static constexpr int kC = 32, kR = 255, kE = 256;

// Static device scratch (graph-capture-safe). No atomics (round-5 lesson).
__device__ float g_q0kv[768];            // [q0 | kc | vc] = W_{q,k,v}·cls + b
__device__ float g_qw[4 * 256];          // (q0_h^T W_k,h)*scale  [h][e]
__device__ float g_s0[4];                // score of key position 0 per head
__device__ float g_qb[4];                // (q0_h · b_k,h)*scale
__device__ float g_m[256 * 4 * 4];       // chunk max   [bc][chunk][h]
__device__ float g_l[256 * 4 * 4];       // chunk sum   [bc][chunk][h]
__device__ float g_part[256 * 4 * 4 * 256]; // partial xbar [bc][chunk][h][e]
__device__ float g_ln[256 * 256];        // LN output per token
__device__ float g_hact[256 * 1024];     // FFN hidden activations
// bf16 weight caches, e8-major transposed: index ((e>>3)*OUT + o)*8 + (e&7).
// Consumers load uint4 at (e8*OUT+t)*16B -> lane-consecutive (round-6 lesson).
// Producer: LDS-tiled transpose with packed 16B stores (round-7/8 lessons).
__device__ unsigned short g_wv_bf[256 * 256];    // OUT=256, IN=256
__device__ unsigned short g_wout_bf[256 * 256];  // OUT=256, IN=256
__device__ unsigned short g_w1_bf[1024 * 256];   // OUT=1024, IN=256
__device__ unsigned short g_w2_bf[256 * 1024];   // OUT=256, IN=1024

__device__ inline unsigned short f2bf(float f) {
  __hip_bfloat16 h = __float2bfloat16(f);
  return __builtin_bit_cast(unsigned short, h);
}
__device__ inline float bflo(unsigned int u) { return __uint_as_float(u << 16); }
__device__ inline float bfhi(unsigned int u) { return __uint_as_float(u & 0xffff0000u); }

// ---- Setup A: one W_qkv row per wave (768 rows / 192 blocks).
//      Single coalesced 1KB load + shfl reduce per wave: full MLP across
//      waves (round-8 lesson: per-wave row LOOPS serialize on waitcnt). ----
__global__ __launch_bounds__(256) void k_setup_rows(const float* __restrict__ cls,
                                                    const float* __restrict__ w_qkv,
                                                    const float* __restrict__ b_qkv) {
  const int t = threadIdx.x, wv = t >> 6, l = t & 63;
  const int row = blockIdx.x * 4 + wv;  // 0..767
  float4 w4 = *((const float4*)(w_qkv + (size_t)row * 256) + l);
  float4 c4 = *((const float4*)cls + l);
  float a = w4.x * c4.x + w4.y * c4.y + w4.z * c4.z + w4.w * c4.w;
#pragma unroll
  for (int m = 1; m < 64; m <<= 1) a += __shfl_xor(a, m);
  if (l == 0) g_q0kv[row] = a + b_qkv[row];
}

// ---- Setup B: blocks 0..3 = per-head qw/s0/qb (independent coalesced row
//      loads, pipelines well); blocks 4..43 = LDS-tiled transposing casts. ----
__global__ __launch_bounds__(256) void k_setup_head(const float* __restrict__ w_qkv,
                                                    const float* __restrict__ b_qkv,
                                                    const float* __restrict__ w_out,
                                                    const float* __restrict__ w1,
                                                    const float* __restrict__ w2) {
  const int t = threadIdx.x, wvi = t >> 6, l = t & 63;
  if (blockIdx.x >= 4) {  // ---- cast tiles: 64 out-rows x 256 in-cols ----
    const int u = blockIdx.x - 4;  // 0..39
    const float* src;
    unsigned short* dst;
    int R, C, o0, e0;
    if (u < 4) { src = w_qkv + 512 * 256; dst = g_wv_bf; R = 256; C = 256; o0 = u * 64; e0 = 0; }
    else if (u < 8) { src = w_out; dst = g_wout_bf; R = 256; C = 256; o0 = (u - 4) * 64; e0 = 0; }
    else if (u < 24) { src = w1; dst = g_w1_bf; R = 1024; C = 256; o0 = (u - 8) * 64; e0 = 0; }
    else { const int v = u - 24; src = w2; dst = g_w2_bf; R = 256; C = 1024; o0 = (v >> 2) * 64; e0 = (v & 3) * 256; }

    __shared__ unsigned short tile[64 * 260];  // 520B row stride: 8B-aligned, 2-way banks (free)
    for (int r = wvi; r < 64; r += 4) {
      float4 v = *((const float4*)(src + (size_t)(o0 + r) * C + e0) + l);
      ushort4 ov;
      ov.x = f2bf(v.x); ov.y = f2bf(v.y); ov.z = f2bf(v.z); ov.w = f2bf(v.w);
      *(ushort4*)&tile[r * 260 + 4 * l] = ov;
    }
    __syncthreads();
    // lane l -> output row o0+l; one packed 16B store per e8: 1KB/wave coalesced
    const int e80 = e0 >> 3;
    for (int e8l = wvi; e8l < 32; e8l += 4) {
      const unsigned int* tp = (const unsigned int*)&tile[l * 260 + e8l * 8];
      uint4 o;
      o.x = tp[0]; o.y = tp[1]; o.z = tp[2]; o.w = tp[3];
      *(uint4*)(dst + ((size_t)(e80 + e8l) * R + o0 + l) * 8) = o;
    }
    return;
  }

  // ---- head block h: qw row + s0/qb from g_q0kv (round-2-proven pattern) ----
  const int h = blockIdx.x;
  __shared__ float q0h[64];
  if (t < 64) q0h[t] = g_q0kv[h * 64 + t];
  __syncthreads();
  float acc = 0.f;
#pragma unroll 8
  for (int j = 0; j < 64; ++j)
    acc += q0h[j] * w_qkv[(size_t)(256 + h * 64 + j) * 256 + t];
  g_qw[h * 256 + t] = acc * 0.125f;
  if (wvi == 0) {
    const float q = q0h[l];
    float pk = q * g_q0kv[256 + h * 64 + l];  // kc includes b_k
    float pb = q * b_qkv[256 + h * 64 + l];
#pragma unroll
    for (int m = 1; m < 64; m <<= 1) {
      pk += __shfl_xor(pk, m);
      pb += __shfl_xor(pb, m);
    }
    if (l == 0) {
      g_s0[h] = pk * 0.125f;
      g_qb[h] = pb * 0.125f;
    }
  }
}

// ---- Attention chunks: scores + chunk softmax + partial weighted sums ----
__global__ __launch_bounds__(256) void k_attn(const float* __restrict__ x,
                                              const int* __restrict__ real_cols,
                                              const int* __restrict__ real_rows) {
  const int bc = blockIdx.x, chunk = blockIdx.y;
  const int b = bc >> 5, c = bc & 31;
  if (c >= real_cols[b]) return;
  const int rr = real_rows[b];
  const int r0 = chunk * 64;
  const int nr = min(64, rr - r0);
  if (nr <= 0) return;

  __shared__ float xs[64][260];  // 1040B row stride: uniform bank windows
  __shared__ float qws[4][256];
  __shared__ float ps[4][64];
  const int t = threadIdx.x, wv = t >> 6, l = t & 63;

#pragma unroll
  for (int i = 0; i < 4; ++i) qws[i][t] = g_qw[i * 256 + t];

  const float* xb = x + ((size_t)bc * kR + r0) * kE;
  for (int r = wv; r < nr; r += 4)
    *(float4*)&xs[r][4 * l] = *(const float4*)(xb + (size_t)r * kE + 4 * l);
  __syncthreads();

  const int h = wv, row = l;
  float acc = 0.f;
  const float4* qrow = (const float4*)&qws[h][0];
  const float4* xrow = (const float4*)&xs[row][0];
#pragma unroll 8
  for (int e4 = 0; e4 < 64; ++e4) {
    float4 q4 = qrow[e4];
    float4 x4 = xrow[e4];
    acc += q4.x * x4.x + q4.y * x4.y + q4.z * x4.z + q4.w * x4.w;
  }
  float s = (row < nr) ? acc + g_qb[h] : -1e30f;
  float mx = s;
#pragma unroll
  for (int m = 1; m < 64; m <<= 1) mx = fmaxf(mx, __shfl_xor(mx, m));
  float p = (row < nr) ? __expf(s - mx) : 0.f;
  float lsum = p;
#pragma unroll
  for (int m = 1; m < 64; m <<= 1) lsum += __shfl_xor(lsum, m);
  ps[h][row] = p;
  if (l == 0) {
    g_m[(bc * 4 + chunk) * 4 + h] = mx;
    g_l[(bc * 4 + chunk) * 4 + h] = lsum;
  }
  __syncthreads();

  float a0 = 0.f, a1 = 0.f, a2 = 0.f, a3 = 0.f;
  for (int r2 = 0; r2 < nr; ++r2) {
    float xv = xs[r2][t];
    a0 += ps[0][r2] * xv;
    a1 += ps[1][r2] * xv;
    a2 += ps[2][r2] * xv;
    a3 += ps[3][r2] * xv;
  }
  float* pp = g_part + (size_t)(bc * 4 + chunk) * 4 * 256;
  pp[0 * 256 + t] = a0;
  pp[1 * 256 + t] = a1;
  pp[2 * 256 + t] = a2;
  pp[3 * 256 + t] = a3;
}

// ---- Tail: merge -> xbar -> ctx -> mha -> LN. 1 token/block, coalesced. ----
__global__ __launch_bounds__(256) void k_tail(const int* __restrict__ real_cols,
                                              const int* __restrict__ real_rows,
                                              const float* __restrict__ b_qkv,
                                              const float* __restrict__ b_out,
                                              const float* __restrict__ ln_g,
                                              const float* __restrict__ ln_b) {
  const int bc = blockIdx.x, b = bc >> 5, c = bc & 31;
  if (c >= real_cols[b]) return;  // g_ln stays stale-but-finite; masked later
  const int rr = real_rows[b];
  const int nch = (rr + 63) >> 6;
  const int t = threadIdx.x, wv = t >> 6, l = t & 63;

  __shared__ float xb[4][256];
  __shared__ float ctxs[256];
  __shared__ float al[4][4];
  __shared__ float p0s[4];
  __shared__ float rb[2][4];

  if (t < 4) {  // flash-merge chunk stats, head h = t
    const int h = t;
    const float s0 = g_s0[h];
    float M = s0;
    for (int ch = 0; ch < nch; ++ch) M = fmaxf(M, g_m[(bc * 4 + ch) * 4 + h]);
    float lt = __expf(s0 - M);
    const float w0 = lt;
    float av[4] = {0.f, 0.f, 0.f, 0.f};
    for (int ch = 0; ch < nch; ++ch) {
      float e = __expf(g_m[(bc * 4 + ch) * 4 + h] - M);
      av[ch] = e;
      lt += g_l[(bc * 4 + ch) * 4 + h] * e;
    }
    const float inv = 1.f / lt;
#pragma unroll
    for (int ch = 0; ch < 4; ++ch) al[h][ch] = av[ch] * inv;
    p0s[h] = w0 * inv;
  }
  __syncthreads();

#pragma unroll
  for (int h = 0; h < 4; ++h) {
    float a = 0.f;
    for (int ch = 0; ch < nch; ++ch)
      a += al[h][ch] * g_part[(size_t)(bc * 4 + ch) * 4 * 256 + h * 256 + t];
    xb[h][t] = a;
  }
  __syncthreads();

  {  // ctx[f=t]; e8-major W_v: load (e8*256+t) -> coalesced
    const int h = wv;
    const float p0 = p0s[h];
    float acc = p0 * g_q0kv[512 + t] + (1.f - p0) * b_qkv[512 + t];
    const uint4* wr = (const uint4*)g_wv_bf;
    const float4* v4p = (const float4*)&xb[h][0];
#pragma unroll 4
    for (int e8 = 0; e8 < 32; ++e8) {
      uint4 w = wr[e8 * 256 + t];
      float4 a = v4p[2 * e8], bb = v4p[2 * e8 + 1];
      acc += bflo(w.x) * a.x + bfhi(w.x) * a.y + bflo(w.y) * a.z + bfhi(w.y) * a.w +
             bflo(w.z) * bb.x + bfhi(w.z) * bb.y + bflo(w.w) * bb.z + bfhi(w.w) * bb.w;
    }
    ctxs[t] = acc;
  }
  __syncthreads();

  float mh;
  {  // mha[g=t]; e8-major W_out
    float acc = b_out[t];
    const uint4* wr = (const uint4*)g_wout_bf;
    const float4* c4 = (const float4*)&ctxs[0];
#pragma unroll 4
    for (int e8 = 0; e8 < 32; ++e8) {
      uint4 w = wr[e8 * 256 + t];
      float4 a = c4[2 * e8], bb = c4[2 * e8 + 1];
      acc += bflo(w.x) * a.x + bfhi(w.x) * a.y + bflo(w.y) * a.z + bfhi(w.y) * a.w +
             bflo(w.z) * bb.x + bfhi(w.z) * bb.y + bflo(w.w) * bb.z + bfhi(w.w) * bb.w;
    }
    mh = acc;
  }

  float s1 = mh, s2 = mh * mh;
#pragma unroll
  for (int m = 1; m < 64; m <<= 1) {
    s1 += __shfl_xor(s1, m);
    s2 += __shfl_xor(s2, m);
  }
  if (l == 0) {
    rb[0][wv] = s1;
    rb[1][wv] = s2;
  }
  __syncthreads();
  const float mu = (rb[0][0] + rb[0][1] + rb[0][2] + rb[0][3]) * (1.f / 256.f);
  const float msq = (rb[1][0] + rb[1][1] + rb[1][2] + rb[1][3]) * (1.f / 256.f);
  const float var = msq - mu * mu;
  g_ln[(size_t)bc * 256 + t] =
      (mh - mu) * rsqrtf(var + 1e-5f) * ln_g[t] + ln_b[t];
}

// ---- FFN1: relu(W1·ln+b1); 8 tokens x 128-f slice; e8-major W1 ----
__global__ __launch_bounds__(256) void k_ffn1(const float* __restrict__ b1,
                                              const int* __restrict__ real_cols) {
  const int tok0 = blockIdx.x * 8;
  const int b = tok0 >> 5, c0 = tok0 & 31;
  if (c0 >= real_cols[b]) return;
  __shared__ float lns[8][256];
  const int t = threadIdx.x;
  const int f0 = blockIdx.y * 128;
#pragma unroll
  for (int i = 0; i < 8; ++i) lns[i][t] = g_ln[(size_t)(tok0 + i) * 256 + t];
  __syncthreads();
  const int f = f0 + (t & 127), half = t >> 7;
  const uint4* wr = (const uint4*)g_w1_bf;
  const float bb = b1[f];
  float acc[4] = {bb, bb, bb, bb};
  for (int e8 = 0; e8 < 32; ++e8) {
    uint4 w = wr[e8 * 1024 + f];  // lanes f..f+63 consecutive -> coalesced
    const float w0 = bflo(w.x), w1v = bfhi(w.x), w2v = bflo(w.y), w3 = bfhi(w.y);
    const float w4v = bflo(w.z), w5 = bfhi(w.z), w6 = bflo(w.w), w7 = bfhi(w.w);
#pragma unroll
    for (int k = 0; k < 4; ++k) {
      const int i = half * 4 + k;
      const float4 a = *(const float4*)&lns[i][8 * e8];
      const float4 bbv = *(const float4*)&lns[i][8 * e8 + 4];
      acc[k] += w0 * a.x + w1v * a.y + w2v * a.z + w3 * a.w +
                w4v * bbv.x + w5 * bbv.y + w6 * bbv.z + w7 * bbv.w;
    }
  }
#pragma unroll
  for (int k = 0; k < 4; ++k)
    g_hact[(size_t)(tok0 + half * 4 + k) * 1024 + f] = fmaxf(acc[k], 0.f);
}

// ---- FFN2 + residual + mask; 8 tokens x 32-e slice; e8-major W2 ----
__global__ __launch_bounds__(256) void k_ffn2(const float* __restrict__ b2,
                                              const int* __restrict__ real_cols,
                                              float* __restrict__ out) {
  const int t = threadIdx.x;
  const int tok0 = blockIdx.x * 8, e0 = blockIdx.y * 32;
  const int b = tok0 >> 5, c0 = tok0 & 31;
  const int ncols = real_cols[b];
  if (c0 >= ncols) {  // whole group invalid: just write the zero mask
    out[(size_t)(tok0 + (t >> 5)) * 256 + e0 + (t & 31)] = 0.f;
    return;
  }
  __shared__ float hs[8][1024];  // 32 KB
#pragma unroll
  for (int i = 0; i < 8; ++i) {
#pragma unroll
    for (int j = 0; j < 4; ++j)
      hs[i][j * 256 + t] = g_hact[(size_t)(tok0 + i) * 1024 + j * 256 + t];
  }
  __syncthreads();
  const int e = e0 + (t & 31), i = t >> 5;
  const int tok = tok0 + i, c = tok & 31;
  const uint4* wr = (const uint4*)g_w2_bf;
  const float4* h4 = (const float4*)&hs[i][0];
  float acc = b2[e];
  for (int f8 = 0; f8 < 128; ++f8) {
    uint4 w = wr[f8 * 256 + e];  // 32 consecutive e x 16B, shared across tokens
    float4 a = h4[2 * f8], bb = h4[2 * f8 + 1];
    acc += bflo(w.x) * a.x + bfhi(w.x) * a.y + bflo(w.y) * a.z + bfhi(w.y) * a.w +
           bflo(w.z) * bb.x + bfhi(w.z) * bb.y + bflo(w.w) * bb.z + bfhi(w.w) * bb.w;
  }
  const float lnv = g_ln[(size_t)tok * 256 + e];
  out[(size_t)tok * 256 + e] = (c < ncols) ? (lnv + acc) : 0.f;
}

extern "C" void kernel_launch(void* const* d_in, const int* in_sizes, int n_in,
                              void* d_out, int out_size, void* d_ws, size_t ws_size,
                              hipStream_t stream) {
  const float* x = (const float*)d_in[0];
  const int* real_cols = (const int*)d_in[1];
  const int* real_rows = (const int*)d_in[2];
  const float* cls = (const float*)d_in[3];
  const float* w_qkv = (const float*)d_in[4];
  const float* b_qkv = (const float*)d_in[5];
  const float* w_out = (const float*)d_in[6];
  const float* b_out = (const float*)d_in[7];
  const float* ln_g = (const float*)d_in[8];
  const float* ln_b = (const float*)d_in[9];
  const float* w1 = (const float*)d_in[10];
  const float* b1 = (const float*)d_in[11];
  const float* w2 = (const float*)d_in[12];
  const float* b2 = (const float*)d_in[13];
  float* out = (float*)d_out;
  (void)in_sizes; (void)n_in; (void)out_size; (void)d_ws; (void)ws_size;

  k_setup_rows<<<192, 256, 0, stream>>>(cls, w_qkv, b_qkv);
  k_setup_head<<<44, 256, 0, stream>>>(w_qkv, b_qkv, w_out, w1, w2);
  k_attn<<<dim3(256, 4), 256, 0, stream>>>(x, real_cols, real_rows);
  k_tail<<<256, 256, 0, stream>>>(real_cols, real_rows, b_qkv, b_out, ln_g, ln_b);
  k_ffn1<<<dim3(32, 8), 256, 0, stream>>>(b1, real_cols);
  k_ffn2<<<dim3(32, 8), 256, 0, stream>>>(b2, real_cols, out);
}